// Round 16
// baseline (199.797 us; speedup 1.0000x reference)
//
#include <hip/hip_runtime.h>
#include <hip/hip_bf16.h>
#include <stdint.h>

#define D_MODEL 1024
#define N_HEADS 16
#define HEAD_DIM 64
#define B_SZ 4
#define T_SEQ 2048
#define BH_TOT (B_SZ * N_HEADS)     // 64
#define M_ROWS (B_SZ * T_SEQ)       // 8192

typedef float floatx4 __attribute__((ext_vector_type(4)));
typedef __bf16 bf16x8 __attribute__((ext_vector_type(8)));

#if __has_builtin(__builtin_amdgcn_exp2f)
#define EXP2(x) __builtin_amdgcn_exp2f(x)
#else
#define EXP2(x) exp2f(x)
#endif

__device__ inline unsigned short f2bf(float f) {
  union { float f; unsigned int u; } c; c.f = f;
  unsigned int u = c.u;
  unsigned int r = (u + 0x7FFFu + ((u >> 16) & 1u)) >> 16;
  return (unsigned short)r;
}

__device__ inline unsigned short bfc(float f) {  // native cvt (RNE)
  return __builtin_bit_cast(unsigned short, (__bf16)f);
}

__device__ inline unsigned int pk2(float lo, float hi) {  // 2xbf16 in u32
  return (unsigned int)bfc(lo) | ((unsigned int)bfc(hi) << 16);
}

__device__ __forceinline__ void gload16(const unsigned short* g,
                                        unsigned short* l) {
  __builtin_amdgcn_global_load_lds(
      (const __attribute__((address_space(1))) void*)g,
      (__attribute__((address_space(3))) void*)l, 16, 0, 0);
}

// ---------------- fp32 [K][N] -> bf16 [N][K] transpose ----------------
__global__ __launch_bounds__(256) void cvt_transpose(
    const float* __restrict__ in, unsigned short* __restrict__ out,
    int K, int N) {
  __shared__ unsigned short tile[32][33];
  const int n0 = blockIdx.x * 32;
  const int k0 = blockIdx.y * 32;
  const int tx = threadIdx.x & 31;
  const int ty = threadIdx.x >> 5;  // 0..7
#pragma unroll
  for (int r = ty; r < 32; r += 8)
    tile[r][tx] = f2bf(in[(size_t)(k0 + r) * N + n0 + tx]);
  __syncthreads();
#pragma unroll
  for (int r = ty; r < 32; r += 8)
    out[(size_t)(n0 + r) * K + k0 + tx] = tile[tx][r];
}

// ---------------- bf16 MFMA GEMM, 128x128 tile, BK=64 ------------------
// r12 structure (no XCD swizzle — r15 showed it neutral/negative here).
// EPI 0: A comes from FP32 x directly — reg-staged with fused bf16
//        convert (2x float4 -> pk2 -> ds_write_b128 to the same swizzled
//        slot the reads expect; write-XOR == read-XOR, srl == row&7).
//        Removes the standalone cvt kernel + 16.8MB write/re-read.
//        Epilogue: Q*QSCALE -> Qb, K -> Kb, V transposed -> Vt.
// EPI 1: A is bf16 (Ob), staged via global_load_lds; fp32 out to Cout.
#define QSCALE 0.1803368801111204f  // 0.125 * log2(e)
template <int EPI>
__global__ __launch_bounds__(256) void gemm_bf16(
    const unsigned short* __restrict__ A, const float* __restrict__ Af32,
    const unsigned short* __restrict__ Bt, int M, int N, int K,
    unsigned short* __restrict__ Qb, unsigned short* __restrict__ Kb,
    unsigned short* __restrict__ Vt, float* __restrict__ Cout) {
  const int bn = blockIdx.x * 128;
  const int bm = blockIdx.y * 128;
  const int tid = threadIdx.x;
  const int lane = tid & 63;
  const int w = tid >> 6;
  const int wr = w >> 1, wc = w & 1;  // 2x2 waves, each 64x64
  const int l15 = lane & 15;
  const int lg = lane >> 4;
  const int l7 = l15 & 7;

  __shared__ unsigned short As[128 * 64];
  __shared__ unsigned short Bs[128 * 64];

  floatx4 acc[4][4] = {};

  const int srl = lane >> 3;               // local staging row 0..7 (=row&7)
  const int scl = (lane & 7) * 8;          // linear source col (elems)
  const int ssw = ((lane & 7) ^ srl) * 8;  // swizzled col slot (u16)

  for (int k0 = 0; k0 < K; k0 += 64) {
    if (EPI == 0) {
      // A: fp32 -> regs (coalesced 256B/row-group), B: gload_lds
      float4 a0[4], a1[4];
#pragma unroll
      for (int p2 = 0; p2 < 4; ++p2) {
        const int rbase = p2 * 32 + w * 8;
        const float* src = &Af32[(size_t)(bm + rbase + srl) * K + k0 + scl];
        a0[p2] = *(const float4*)src;
        a1[p2] = *(const float4*)(src + 4);
        gload16(&Bt[(size_t)(bn + rbase + srl) * K + k0 + ssw],
                &Bs[rbase * 64]);
      }
#pragma unroll
      for (int p2 = 0; p2 < 4; ++p2) {
        const int rbase = p2 * 32 + w * 8;
        uint4 wv;
        wv.x = pk2(a0[p2].x, a0[p2].y);
        wv.y = pk2(a0[p2].z, a0[p2].w);
        wv.z = pk2(a1[p2].x, a1[p2].y);
        wv.w = pk2(a1[p2].z, a1[p2].w);
        *(uint4*)&As[(size_t)(rbase + srl) * 64 + ssw] = wv;
      }
    } else {
#pragma unroll
      for (int p2 = 0; p2 < 4; ++p2) {
        const int rbase = p2 * 32 + w * 8;
        gload16(&A[(size_t)(bm + rbase + srl) * K + k0 + ssw], &As[rbase * 64]);
        gload16(&Bt[(size_t)(bn + rbase + srl) * K + k0 + ssw],
                &Bs[rbase * 64]);
      }
    }
    __syncthreads();

#pragma unroll
    for (int kk = 0; kk < 2; ++kk) {
      bf16x8 af[4], bfr[4];
#pragma unroll
      for (int mt = 0; mt < 4; ++mt)
        af[mt] = *(const bf16x8*)&As[(wr * 64 + mt * 16 + l15) * 64 +
                                     (((kk * 4 + lg) ^ l7) << 3)];
#pragma unroll
      for (int nt = 0; nt < 4; ++nt)
        bfr[nt] = *(const bf16x8*)&Bs[(wc * 64 + nt * 16 + l15) * 64 +
                                      (((kk * 4 + lg) ^ l7) << 3)];
#pragma unroll
      for (int mt = 0; mt < 4; ++mt)
#pragma unroll
        for (int nt = 0; nt < 4; ++nt)
          acc[mt][nt] = __builtin_amdgcn_mfma_f32_16x16x32_bf16(
              af[mt], bfr[nt], acc[mt][nt], 0, 0, 0);
    }
    __syncthreads();
  }

#pragma unroll
  for (int mt = 0; mt < 4; ++mt)
#pragma unroll
    for (int nt = 0; nt < 4; ++nt) {
      const int n = bn + wc * 64 + nt * 16 + l15;
      const int m0 = bm + wr * 64 + mt * 16 + lg * 4;
      if (EPI == 0 && (n >> 10) == 2) {
        // V: write transposed, vectorized over the 4 consecutive t
        int b = m0 >> 11;
        int t = m0 & (T_SEQ - 1);
        int nn = n & (D_MODEL - 1);
        int h = nn >> 6;
        int dh = nn & 63;
        ushort4 v4;
        v4.x = bfc(acc[mt][nt][0]);
        v4.y = bfc(acc[mt][nt][1]);
        v4.z = bfc(acc[mt][nt][2]);
        v4.w = bfc(acc[mt][nt][3]);
        *(ushort4*)&Vt[((size_t)((b * N_HEADS + h) * HEAD_DIM) + dh) * T_SEQ +
                       t] = v4;
      } else {
#pragma unroll
        for (int i = 0; i < 4; ++i) {
          int m = m0 + i;
          float v = acc[mt][nt][i];
          if (EPI == 0) {
            int b = m >> 11;
            int t = m & (T_SEQ - 1);
            int part = n >> 10;  // 0=q 1=k
            int nn = n & (D_MODEL - 1);
            int h = nn >> 6;
            int dh = nn & 63;
            size_t idx =
                ((size_t)(b * N_HEADS + h) * T_SEQ + t) * HEAD_DIM + dh;
            if (part == 0)
              Qb[idx] = bfc(v * QSCALE);
            else
              Kb[idx] = bfc(v);
          } else {
            Cout[(size_t)m * N + n] = v;
          }
        }
      }
    }
}

// ---------------- causal flash attention (exact r12 config: 80us) -------
// block (head, p in 0..7): phase 0 = rows [128p,128p+128), phase 1 =
// mirror; 34 uniform 64-key steps. 4 waves x 32 q-rows. gload_lds
// double-buffer with pre-swizzled source, 1 barrier/step. Swapped MFMA
// S^T=mfma(K,Q), in-lane softmax, defer-max THR=8, P via ds_write_b64 ->
// b128, PV with V^T fragments.
__global__ __launch_bounds__(256) void attn_fwd(
    const unsigned short* __restrict__ Qb, const unsigned short* __restrict__ Kb,
    const unsigned short* __restrict__ Vt, unsigned short* __restrict__ Ob) {
  const int head = blockIdx.x;  // 0..63
  const int p = blockIdx.y;     // 0..7
  const int tid = threadIdx.x;
  const int wid = tid >> 6;
  const int lane = tid & 63;
  const int l15 = lane & 15;
  const int lg = lane >> 4;
  const int l7 = l15 & 7;
  const int b = head >> 4;
  const int h = head & 15;

  const unsigned short* Qh = Qb + (size_t)head * T_SEQ * HEAD_DIM;
  const unsigned short* Kh = Kb + (size_t)head * T_SEQ * HEAD_DIM;
  const unsigned short* Vh = Vt + (size_t)head * HEAD_DIM * T_SEQ;

  __shared__ unsigned short Ks[2][64 * 64];
  __shared__ unsigned short Vs[2][64 * 64];
  __shared__ unsigned short Ps[4 * 2 * 16 * 64];  // wave-private, swizzled

  const int swz8 = (((lane & 7) ^ (lane >> 3)) << 3);  // u16 units
  const int srow = wid * 16 + (lane >> 3);
  const size_t kLane0 = (size_t)srow * HEAD_DIM + swz8;
  const size_t kLane1 = (size_t)(srow + 8) * HEAD_DIM + swz8;
  const size_t vLane0 = (size_t)srow * T_SEQ + swz8;
  const size_t vLane1 = (size_t)(srow + 8) * T_SEQ + swz8;
  const int ldsW = wid * 1024;  // u16: wave's 2KB region per tile

  int kfo0[4], kfo1[4], vfo[2][4];
#pragma unroll
  for (int c = 0; c < 4; ++c) {
    kfo0[c] = (c * 16 + l15) * 64 + ((lg ^ l7) << 3);
    kfo1[c] = (c * 16 + l15) * 64 + (((4 + lg) ^ l7) << 3);
  }
#pragma unroll
  for (int kc = 0; kc < 2; ++kc)
#pragma unroll
    for (int d = 0; d < 4; ++d)
      vfo[kc][d] = (d * 16 + l15) * 64 + (((kc * 4 + lg) ^ l7) << 3);
  int pwo[4];
#pragma unroll
  for (int c = 0; c < 4; ++c)
    pwo[c] = l15 * 64 + (((2 * c + (lg >> 1)) ^ l7) << 3) + (lg & 1) * 4;
  const int pro0 = l15 * 64 + ((lg ^ l7) << 3);
  const int pro1 = l15 * 64 + (((4 + lg) ^ l7) << 3);

  for (int ph = 0; ph < 2; ++ph) {
    const int rbase = (ph == 0) ? p * 128 : 2048 - 128 * (p + 1);
    const int nst = (ph == 0) ? 2 * p + 2 : 32 - 2 * p;
    const int q0 = rbase + wid * 32;

    bf16x8 qf[2][2];
#pragma unroll
    for (int t = 0; t < 2; ++t)
#pragma unroll
      for (int c = 0; c < 2; ++c)
        qf[t][c] = *(const bf16x8*)&Qh[(size_t)(q0 + t * 16 + l15) * 64 +
                                       c * 32 + lg * 8];

    floatx4 o[2][4] = {};
    float m_run[2] = {-1e30f, -1e30f};
    float l_part[2] = {0.f, 0.f};

    __syncthreads();  // previous phase's reads fully done before restaging
    gload16(Kh + kLane0, &Ks[0][ldsW]);
    gload16(Kh + kLane1, &Ks[0][ldsW + 512]);
    gload16(Vh + vLane0, &Vs[0][ldsW]);
    gload16(Vh + vLane1, &Vs[0][ldsW + 512]);

    int cur = 0;
    for (int kb = 0; kb < nst; ++kb, cur ^= 1) {
      const int kbase = kb * 64;
      __syncthreads();  // drains vmcnt -> buf[cur] fully staged, all waves

      if (kb + 1 < nst) {  // issue next chunk into idle buffer (hidden)
        const size_t ko = (size_t)(kbase + 64) * HEAD_DIM;
        const int vo = kbase + 64;
        gload16(Kh + ko + kLane0, &Ks[cur ^ 1][ldsW]);
        gload16(Kh + ko + kLane1, &Ks[cur ^ 1][ldsW + 512]);
        gload16(Vh + vo + vLane0, &Vs[cur ^ 1][ldsW]);
        gload16(Vh + vo + vLane1, &Vs[cur ^ 1][ldsW + 512]);
      }

      if (kbase <= q0 + 31) {  // causal work remains for this wave
        const unsigned short* Kc = Ks[cur];
        const unsigned short* Vc = Vs[cur];
        bf16x8 kf0[4], kf1[4];
#pragma unroll
        for (int c = 0; c < 4; ++c) {
          kf0[c] = *(const bf16x8*)&Kc[kfo0[c]];
          kf1[c] = *(const bf16x8*)&Kc[kfo1[c]];
        }
        bf16x8 vf[2][4];
#pragma unroll
        for (int kc = 0; kc < 2; ++kc)
#pragma unroll
          for (int d = 0; d < 4; ++d) vf[kc][d] = *(const bf16x8*)&Vc[vfo[kc][d]];

        // S^T = K . Q^T : D[row = k_local = c*16+lg*4+i, col = q = l15]
        floatx4 st_[2][4] = {};
        __builtin_amdgcn_s_setprio(1);
#pragma unroll
        for (int c = 0; c < 4; ++c) {
          st_[0][c] = __builtin_amdgcn_mfma_f32_16x16x32_bf16(kf0[c], qf[0][0], st_[0][c], 0, 0, 0);
          st_[0][c] = __builtin_amdgcn_mfma_f32_16x16x32_bf16(kf1[c], qf[0][1], st_[0][c], 0, 0, 0);
          st_[1][c] = __builtin_amdgcn_mfma_f32_16x16x32_bf16(kf0[c], qf[1][0], st_[1][c], 0, 0, 0);
          st_[1][c] = __builtin_amdgcn_mfma_f32_16x16x32_bf16(kf1[c], qf[1][1], st_[1][c], 0, 0, 0);
        }
        __builtin_amdgcn_s_setprio(0);

        if (kbase + 63 > q0) {  // causal mask: k_local > q - kbase
#pragma unroll
          for (int t = 0; t < 2; ++t) {
            const int thr = q0 + t * 16 + l15 - kbase;
#pragma unroll
            for (int c = 0; c < 4; ++c)
#pragma unroll
              for (int i = 0; i < 4; ++i)
                if (c * 16 + lg * 4 + i > thr) st_[t][c][i] = -1e30f;
          }
        }

        float lmax[2];
        bool need = false;
#pragma unroll
        for (int t = 0; t < 2; ++t) {
          float v0 = fmaxf(fmaxf(st_[t][0][0], st_[t][0][1]),
                           fmaxf(st_[t][0][2], st_[t][0][3]));
          float v1 = fmaxf(fmaxf(st_[t][1][0], st_[t][1][1]),
                           fmaxf(st_[t][1][2], st_[t][1][3]));
          float v2 = fmaxf(fmaxf(st_[t][2][0], st_[t][2][1]),
                           fmaxf(st_[t][2][2], st_[t][2][3]));
          float v3 = fmaxf(fmaxf(st_[t][3][0], st_[t][3][1]),
                           fmaxf(st_[t][3][2], st_[t][3][3]));
          lmax[t] = fmaxf(fmaxf(v0, v1), fmaxf(v2, v3));
          need |= (lmax[t] > m_run[t] + 8.0f);
        }
        if (__any(need)) {
#pragma unroll
          for (int t = 0; t < 2; ++t) {
            float pm = lmax[t];
            pm = fmaxf(pm, __shfl_xor(pm, 16));
            pm = fmaxf(pm, __shfl_xor(pm, 32));
            float mnew = fmaxf(m_run[t], pm);
            float alpha = EXP2(m_run[t] - mnew);
            m_run[t] = mnew;
            l_part[t] *= alpha;
#pragma unroll
            for (int c = 0; c < 4; ++c) o[t][c] *= alpha;
          }
        }

#pragma unroll
        for (int t = 0; t < 2; ++t) {
          const int tb = (wid * 2 + t) * 1024;
          float sum = 0.f;
#pragma unroll
          for (int c = 0; c < 4; ++c) {
#pragma unroll
            for (int i = 0; i < 4; ++i) {
              st_[t][c][i] = EXP2(st_[t][c][i] - m_run[t]);
              sum += st_[t][c][i];
            }
            uint2 wv;
            wv.x = pk2(st_[t][c][0], st_[t][c][1]);
            wv.y = pk2(st_[t][c][2], st_[t][c][3]);
            *(uint2*)&Ps[tb + pwo[c]] = wv;  // ds_write_b64, swizzled
          }
          l_part[t] += sum;
        }

        // O^T += V^T . P^T
        __builtin_amdgcn_s_setprio(1);
#pragma unroll
        for (int t = 0; t < 2; ++t) {
          const int tb = (wid * 2 + t) * 1024;
          bf16x8 pb0 = *(const bf16x8*)&Ps[tb + pro0];
          bf16x8 pb1 = *(const bf16x8*)&Ps[tb + pro1];
#pragma unroll
          for (int dt = 0; dt < 4; ++dt) {
            o[t][dt] = __builtin_amdgcn_mfma_f32_16x16x32_bf16(vf[0][dt], pb0, o[t][dt], 0, 0, 0);
            o[t][dt] = __builtin_amdgcn_mfma_f32_16x16x32_bf16(vf[1][dt], pb1, o[t][dt], 0, 0, 0);
          }
        }
        __builtin_amdgcn_s_setprio(0);
      }
    }

    // epilogue: reduce 4 lg-lane l partials via 2 shuffles; write O
#pragma unroll
    for (int t = 0; t < 2; ++t) {
      float l = l_part[t];
      l += __shfl_xor(l, 16);
      l += __shfl_xor(l, 32);
      float inv = 1.0f / l;
      int q = q0 + t * 16 + l15;
      size_t base = ((size_t)(b * T_SEQ + q)) * D_MODEL + h * HEAD_DIM;
#pragma unroll
      for (int dt = 0; dt < 4; ++dt) {
        unsigned int u0 = pk2(o[t][dt][0] * inv, o[t][dt][1] * inv);
        unsigned int u1 = pk2(o[t][dt][2] * inv, o[t][dt][3] * inv);
        *(unsigned int*)&Ob[base + dt * 16 + lg * 4] = u0;
        *(unsigned int*)&Ob[base + dt * 16 + lg * 4 + 2] = u1;
      }
    }
  }
}

extern "C" void kernel_launch(void* const* d_in, const int* in_sizes, int n_in,
                              void* d_out, int out_size, void* d_ws,
                              size_t ws_size, hipStream_t stream) {
  const float* x = (const float*)d_in[0];
  const float* w_qkv = (const float*)d_in[1];
  const float* w_proj = (const float*)d_in[2];
  float* out = (float*)d_out;

  char* ws = (char*)d_ws;
  size_t off = 0;
  unsigned short* wqkv_t = (unsigned short*)(ws + off);
  off += (size_t)D_MODEL * 3 * D_MODEL * 2;
  unsigned short* wproj_t = (unsigned short*)(ws + off);
  off += (size_t)D_MODEL * D_MODEL * 2;
  unsigned short* Qb = (unsigned short*)(ws + off);
  off += (size_t)BH_TOT * T_SEQ * HEAD_DIM * 2;
  unsigned short* Kb = (unsigned short*)(ws + off);
  off += (size_t)BH_TOT * T_SEQ * HEAD_DIM * 2;
  unsigned short* Vt = (unsigned short*)(ws + off);
  off += (size_t)BH_TOT * T_SEQ * HEAD_DIM * 2;
  unsigned short* Ob = (unsigned short*)(ws + off);
  off += (size_t)M_ROWS * D_MODEL * 2;

  cvt_transpose<<<dim3(3 * D_MODEL / 32, D_MODEL / 32), 256, 0, stream>>>(
      w_qkv, wqkv_t, D_MODEL, 3 * D_MODEL);
  cvt_transpose<<<dim3(D_MODEL / 32, D_MODEL / 32), 256, 0, stream>>>(
      w_proj, wproj_t, D_MODEL, D_MODEL);

  gemm_bf16<0><<<dim3(3 * D_MODEL / 128, M_ROWS / 128), 256, 0, stream>>>(
      nullptr, x, wqkv_t, M_ROWS, 3 * D_MODEL, D_MODEL, Qb, Kb, Vt, nullptr);

  attn_fwd<<<dim3(BH_TOT, 8), 256, 0, stream>>>(Qb, Kb, Vt, Ob);

  gemm_bf16<1><<<dim3(D_MODEL / 128, M_ROWS / 128), 256, 0, stream>>>(
      Ob, nullptr, wproj_t, M_ROWS, D_MODEL, D_MODEL, nullptr, nullptr,
      nullptr, out);
}

// Round 18
// 187.833 us; speedup vs baseline: 1.0637x; 1.0637x over previous
//
#include <hip/hip_runtime.h>
#include <hip/hip_bf16.h>
#include <stdint.h>

#define D_MODEL 1024
#define N_HEADS 16
#define HEAD_DIM 64
#define B_SZ 4
#define T_SEQ 2048
#define BH_TOT (B_SZ * N_HEADS)     // 64
#define M_ROWS (B_SZ * T_SEQ)       // 8192

typedef float floatx4 __attribute__((ext_vector_type(4)));
typedef __bf16 bf16x8 __attribute__((ext_vector_type(8)));

#if __has_builtin(__builtin_amdgcn_exp2f)
#define EXP2(x) __builtin_amdgcn_exp2f(x)
#else
#define EXP2(x) exp2f(x)
#endif

__device__ inline unsigned short f2bf(float f) {
  union { float f; unsigned int u; } c; c.f = f;
  unsigned int u = c.u;
  unsigned int r = (u + 0x7FFFu + ((u >> 16) & 1u)) >> 16;
  return (unsigned short)r;
}

__device__ inline unsigned short bfc(float f) {  // native cvt (RNE)
  return __builtin_bit_cast(unsigned short, (__bf16)f);
}

__device__ inline unsigned int pk2(float lo, float hi) {  // 2xbf16 in u32
  return (unsigned int)bfc(lo) | ((unsigned int)bfc(hi) << 16);
}

__device__ __forceinline__ void gload16(const unsigned short* g,
                                        unsigned short* l) {
  __builtin_amdgcn_global_load_lds(
      (const __attribute__((address_space(1))) void*)g,
      (__attribute__((address_space(3))) void*)l, 16, 0, 0);
}

// ---------------- fp32 -> bf16 convert (no transpose) ----------------
__global__ void cvt_f32_bf16(const float* __restrict__ in,
                             unsigned short* __restrict__ out, int n) {
  int i = (blockIdx.x * blockDim.x + threadIdx.x) * 4;
  if (i + 3 < n) {
    float4 v = *(const float4*)(in + i);
    out[i + 0] = f2bf(v.x);
    out[i + 1] = f2bf(v.y);
    out[i + 2] = f2bf(v.z);
    out[i + 3] = f2bf(v.w);
  } else {
    for (; i < n; ++i) out[i] = f2bf(in[i]);
  }
}

// ---------------- fp32 [K][N] -> bf16 [N][K] transpose ----------------
__global__ __launch_bounds__(256) void cvt_transpose(
    const float* __restrict__ in, unsigned short* __restrict__ out,
    int K, int N) {
  __shared__ unsigned short tile[32][33];
  const int n0 = blockIdx.x * 32;
  const int k0 = blockIdx.y * 32;
  const int tx = threadIdx.x & 31;
  const int ty = threadIdx.x >> 5;  // 0..7
#pragma unroll
  for (int r = ty; r < 32; r += 8)
    tile[r][tx] = f2bf(in[(size_t)(k0 + r) * N + n0 + tx]);
  __syncthreads();
#pragma unroll
  for (int r = ty; r < 32; r += 8)
    out[(size_t)(n0 + r) * K + k0 + tx] = tile[tx][r];
}

// ---------------- bf16 MFMA GEMM, 128x128 tile, BK=64 ------------------
// global_load_lds staging with PRE-SWIZZLED source (slot^=row&7): linear
// LDS [128][64] u16, 128B rows = full bank wrap -> conflict-free b128
// fragment reads via the same XOR. 16 K-steps (half the barrier drains).
// EPI 0: qkv epilogue. Q scaled by 0.125*log2e -> Qb[bh][t][64];
//        K -> Kb[bh][t][64]; V written TRANSPOSED to Vt[bh][64][t].
#define QSCALE 0.1803368801111204f  // 0.125 * log2(e)
template <int EPI>
__global__ __launch_bounds__(256) void gemm_bf16(
    const unsigned short* __restrict__ A,
    const unsigned short* __restrict__ Bt, int M, int N, int K,
    unsigned short* __restrict__ Qb, unsigned short* __restrict__ Kb,
    unsigned short* __restrict__ Vt, float* __restrict__ Cout) {
  const int bn = blockIdx.x * 128;
  const int bm = blockIdx.y * 128;
  const int tid = threadIdx.x;
  const int lane = tid & 63;
  const int w = tid >> 6;
  const int wr = w >> 1, wc = w & 1;  // 2x2 waves, each 64x64
  const int l15 = lane & 15;
  const int lg = lane >> 4;
  const int l7 = l15 & 7;

  __shared__ unsigned short As[128 * 64];
  __shared__ unsigned short Bs[128 * 64];

  floatx4 acc[4][4] = {};

  const int srl = lane >> 3;                    // local staging row 0..7
  const int ssw = ((lane & 7) ^ srl) * 8;       // swizzled source col (u16)

  for (int k0 = 0; k0 < K; k0 += 64) {
#pragma unroll
    for (int p2 = 0; p2 < 4; ++p2) {
      const int rbase = p2 * 32 + w * 8;
      gload16(&A[(size_t)(bm + rbase + srl) * K + k0 + ssw], &As[rbase * 64]);
      gload16(&Bt[(size_t)(bn + rbase + srl) * K + k0 + ssw], &Bs[rbase * 64]);
    }
    __syncthreads();

#pragma unroll
    for (int kk = 0; kk < 2; ++kk) {
      bf16x8 af[4], bfr[4];
#pragma unroll
      for (int mt = 0; mt < 4; ++mt)
        af[mt] = *(const bf16x8*)&As[(wr * 64 + mt * 16 + l15) * 64 +
                                     (((kk * 4 + lg) ^ l7) << 3)];
#pragma unroll
      for (int nt = 0; nt < 4; ++nt)
        bfr[nt] = *(const bf16x8*)&Bs[(wc * 64 + nt * 16 + l15) * 64 +
                                      (((kk * 4 + lg) ^ l7) << 3)];
#pragma unroll
      for (int mt = 0; mt < 4; ++mt)
#pragma unroll
        for (int nt = 0; nt < 4; ++nt)
          acc[mt][nt] = __builtin_amdgcn_mfma_f32_16x16x32_bf16(
              af[mt], bfr[nt], acc[mt][nt], 0, 0, 0);
    }
    __syncthreads();
  }

#pragma unroll
  for (int mt = 0; mt < 4; ++mt)
#pragma unroll
    for (int nt = 0; nt < 4; ++nt) {
      const int n = bn + wc * 64 + nt * 16 + l15;
      const int m0 = bm + wr * 64 + mt * 16 + lg * 4;
      if (EPI == 0 && (n >> 10) == 2) {
        // V: write transposed, vectorized over the 4 consecutive t
        int b = m0 >> 11;
        int t = m0 & (T_SEQ - 1);
        int nn = n & (D_MODEL - 1);
        int h = nn >> 6;
        int dh = nn & 63;
        ushort4 v4;
        v4.x = bfc(acc[mt][nt][0]);
        v4.y = bfc(acc[mt][nt][1]);
        v4.z = bfc(acc[mt][nt][2]);
        v4.w = bfc(acc[mt][nt][3]);
        *(ushort4*)&Vt[((size_t)((b * N_HEADS + h) * HEAD_DIM) + dh) * T_SEQ +
                       t] = v4;
      } else {
#pragma unroll
        for (int i = 0; i < 4; ++i) {
          int m = m0 + i;
          float v = acc[mt][nt][i];
          if (EPI == 0) {
            int b = m >> 11;
            int t = m & (T_SEQ - 1);
            int part = n >> 10;  // 0=q 1=k
            int nn = n & (D_MODEL - 1);
            int h = nn >> 6;
            int dh = nn & 63;
            size_t idx =
                ((size_t)(b * N_HEADS + h) * T_SEQ + t) * HEAD_DIM + dh;
            if (part == 0)
              Qb[idx] = bfc(v * QSCALE);
            else
              Kb[idx] = bfc(v);
          } else {
            Cout[(size_t)m * N + n] = v;
          }
        }
      }
    }
}

// ---------------- causal flash attention (r12 config: 80us) -------------
// block (head, p in 0..7): phase 0 = rows [128p,128p+128), phase 1 =
// mirror; 34 uniform 64-key steps. 4 waves x 32 q-rows. gload_lds
// double-buffer with pre-swizzled source, 1 barrier/step. Swapped MFMA
// S^T=mfma(K,Q), in-lane softmax, defer-max THR=8, P via ds_write_b64 ->
// b128, PV with V^T fragments.
__global__ __launch_bounds__(256) void attn_fwd(
    const unsigned short* __restrict__ Qb, const unsigned short* __restrict__ Kb,
    const unsigned short* __restrict__ Vt, unsigned short* __restrict__ Ob) {
  const int head = blockIdx.x;  // 0..63
  const int p = blockIdx.y;     // 0..7
  const int tid = threadIdx.x;
  const int wid = tid >> 6;
  const int lane = tid & 63;
  const int l15 = lane & 15;
  const int lg = lane >> 4;
  const int l7 = l15 & 7;
  const int b = head >> 4;
  const int h = head & 15;

  const unsigned short* Qh = Qb + (size_t)head * T_SEQ * HEAD_DIM;
  const unsigned short* Kh = Kb + (size_t)head * T_SEQ * HEAD_DIM;
  const unsigned short* Vh = Vt + (size_t)head * HEAD_DIM * T_SEQ;

  __shared__ unsigned short Ks[2][64 * 64];
  __shared__ unsigned short Vs[2][64 * 64];
  __shared__ unsigned short Ps[4 * 2 * 16 * 64];  // wave-private, swizzled

  const int swz8 = (((lane & 7) ^ (lane >> 3)) << 3);  // u16 units
  const int srow = wid * 16 + (lane >> 3);
  const size_t kLane0 = (size_t)srow * HEAD_DIM + swz8;
  const size_t kLane1 = (size_t)(srow + 8) * HEAD_DIM + swz8;
  const size_t vLane0 = (size_t)srow * T_SEQ + swz8;
  const size_t vLane1 = (size_t)(srow + 8) * T_SEQ + swz8;
  const int ldsW = wid * 1024;  // u16: wave's 2KB region per tile

  int kfo0[4], kfo1[4], vfo[2][4];
#pragma unroll
  for (int c = 0; c < 4; ++c) {
    kfo0[c] = (c * 16 + l15) * 64 + ((lg ^ l7) << 3);
    kfo1[c] = (c * 16 + l15) * 64 + (((4 + lg) ^ l7) << 3);
  }
#pragma unroll
  for (int kc = 0; kc < 2; ++kc)
#pragma unroll
    for (int d = 0; d < 4; ++d)
      vfo[kc][d] = (d * 16 + l15) * 64 + (((kc * 4 + lg) ^ l7) << 3);
  int pwo[4];
#pragma unroll
  for (int c = 0; c < 4; ++c)
    pwo[c] = l15 * 64 + (((2 * c + (lg >> 1)) ^ l7) << 3) + (lg & 1) * 4;
  const int pro0 = l15 * 64 + ((lg ^ l7) << 3);
  const int pro1 = l15 * 64 + (((4 + lg) ^ l7) << 3);

  for (int ph = 0; ph < 2; ++ph) {
    const int rbase = (ph == 0) ? p * 128 : 2048 - 128 * (p + 1);
    const int nst = (ph == 0) ? 2 * p + 2 : 32 - 2 * p;
    const int q0 = rbase + wid * 32;

    bf16x8 qf[2][2];
#pragma unroll
    for (int t = 0; t < 2; ++t)
#pragma unroll
      for (int c = 0; c < 2; ++c)
        qf[t][c] = *(const bf16x8*)&Qh[(size_t)(q0 + t * 16 + l15) * 64 +
                                       c * 32 + lg * 8];

    floatx4 o[2][4] = {};
    float m_run[2] = {-1e30f, -1e30f};
    float l_part[2] = {0.f, 0.f};

    __syncthreads();  // previous phase's reads fully done before restaging
    gload16(Kh + kLane0, &Ks[0][ldsW]);
    gload16(Kh + kLane1, &Ks[0][ldsW + 512]);
    gload16(Vh + vLane0, &Vs[0][ldsW]);
    gload16(Vh + vLane1, &Vs[0][ldsW + 512]);

    int cur = 0;
    for (int kb = 0; kb < nst; ++kb, cur ^= 1) {
      const int kbase = kb * 64;
      __syncthreads();  // drains vmcnt -> buf[cur] fully staged, all waves

      if (kb + 1 < nst) {  // issue next chunk into idle buffer (hidden)
        const size_t ko = (size_t)(kbase + 64) * HEAD_DIM;
        const int vo = kbase + 64;
        gload16(Kh + ko + kLane0, &Ks[cur ^ 1][ldsW]);
        gload16(Kh + ko + kLane1, &Ks[cur ^ 1][ldsW + 512]);
        gload16(Vh + vo + vLane0, &Vs[cur ^ 1][ldsW]);
        gload16(Vh + vo + vLane1, &Vs[cur ^ 1][ldsW + 512]);
      }

      if (kbase <= q0 + 31) {  // causal work remains for this wave
        const unsigned short* Kc = Ks[cur];
        const unsigned short* Vc = Vs[cur];
        bf16x8 kf0[4], kf1[4];
#pragma unroll
        for (int c = 0; c < 4; ++c) {
          kf0[c] = *(const bf16x8*)&Kc[kfo0[c]];
          kf1[c] = *(const bf16x8*)&Kc[kfo1[c]];
        }
        bf16x8 vf[2][4];
#pragma unroll
        for (int kc = 0; kc < 2; ++kc)
#pragma unroll
          for (int d = 0; d < 4; ++d) vf[kc][d] = *(const bf16x8*)&Vc[vfo[kc][d]];

        // S^T = K . Q^T : D[row = k_local = c*16+lg*4+i, col = q = l15]
        floatx4 st_[2][4] = {};
        __builtin_amdgcn_s_setprio(1);
#pragma unroll
        for (int c = 0; c < 4; ++c) {
          st_[0][c] = __builtin_amdgcn_mfma_f32_16x16x32_bf16(kf0[c], qf[0][0], st_[0][c], 0, 0, 0);
          st_[0][c] = __builtin_amdgcn_mfma_f32_16x16x32_bf16(kf1[c], qf[0][1], st_[0][c], 0, 0, 0);
          st_[1][c] = __builtin_amdgcn_mfma_f32_16x16x32_bf16(kf0[c], qf[1][0], st_[1][c], 0, 0, 0);
          st_[1][c] = __builtin_amdgcn_mfma_f32_16x16x32_bf16(kf1[c], qf[1][1], st_[1][c], 0, 0, 0);
        }
        __builtin_amdgcn_s_setprio(0);

        if (kbase + 63 > q0) {  // causal mask: k_local > q - kbase
#pragma unroll
          for (int t = 0; t < 2; ++t) {
            const int thr = q0 + t * 16 + l15 - kbase;
#pragma unroll
            for (int c = 0; c < 4; ++c)
#pragma unroll
              for (int i = 0; i < 4; ++i)
                if (c * 16 + lg * 4 + i > thr) st_[t][c][i] = -1e30f;
          }
        }

        float lmax[2];
        bool need = false;
#pragma unroll
        for (int t = 0; t < 2; ++t) {
          float v0 = fmaxf(fmaxf(st_[t][0][0], st_[t][0][1]),
                           fmaxf(st_[t][0][2], st_[t][0][3]));
          float v1 = fmaxf(fmaxf(st_[t][1][0], st_[t][1][1]),
                           fmaxf(st_[t][1][2], st_[t][1][3]));
          float v2 = fmaxf(fmaxf(st_[t][2][0], st_[t][2][1]),
                           fmaxf(st_[t][2][2], st_[t][2][3]));
          float v3 = fmaxf(fmaxf(st_[t][3][0], st_[t][3][1]),
                           fmaxf(st_[t][3][2], st_[t][3][3]));
          lmax[t] = fmaxf(fmaxf(v0, v1), fmaxf(v2, v3));
          need |= (lmax[t] > m_run[t] + 8.0f);
        }
        if (__any(need)) {
#pragma unroll
          for (int t = 0; t < 2; ++t) {
            float pm = lmax[t];
            pm = fmaxf(pm, __shfl_xor(pm, 16));
            pm = fmaxf(pm, __shfl_xor(pm, 32));
            float mnew = fmaxf(m_run[t], pm);
            float alpha = EXP2(m_run[t] - mnew);
            m_run[t] = mnew;
            l_part[t] *= alpha;
#pragma unroll
            for (int c = 0; c < 4; ++c) o[t][c] *= alpha;
          }
        }

#pragma unroll
        for (int t = 0; t < 2; ++t) {
          const int tb = (wid * 2 + t) * 1024;
          float sum = 0.f;
#pragma unroll
          for (int c = 0; c < 4; ++c) {
#pragma unroll
            for (int i = 0; i < 4; ++i) {
              st_[t][c][i] = EXP2(st_[t][c][i] - m_run[t]);
              sum += st_[t][c][i];
            }
            uint2 wv;
            wv.x = pk2(st_[t][c][0], st_[t][c][1]);
            wv.y = pk2(st_[t][c][2], st_[t][c][3]);
            *(uint2*)&Ps[tb + pwo[c]] = wv;  // ds_write_b64, swizzled
          }
          l_part[t] += sum;
        }

        // O^T += V^T . P^T
        __builtin_amdgcn_s_setprio(1);
#pragma unroll
        for (int t = 0; t < 2; ++t) {
          const int tb = (wid * 2 + t) * 1024;
          bf16x8 pb0 = *(const bf16x8*)&Ps[tb + pro0];
          bf16x8 pb1 = *(const bf16x8*)&Ps[tb + pro1];
#pragma unroll
          for (int dt = 0; dt < 4; ++dt) {
            o[t][dt] = __builtin_amdgcn_mfma_f32_16x16x32_bf16(vf[0][dt], pb0, o[t][dt], 0, 0, 0);
            o[t][dt] = __builtin_amdgcn_mfma_f32_16x16x32_bf16(vf[1][dt], pb1, o[t][dt], 0, 0, 0);
          }
        }
        __builtin_amdgcn_s_setprio(0);
      }
    }

    // epilogue: reduce 4 lg-lane l partials via 2 shuffles; write O
#pragma unroll
    for (int t = 0; t < 2; ++t) {
      float l = l_part[t];
      l += __shfl_xor(l, 16);
      l += __shfl_xor(l, 32);
      float inv = 1.0f / l;
      int q = q0 + t * 16 + l15;
      size_t base = ((size_t)(b * T_SEQ + q)) * D_MODEL + h * HEAD_DIM;
#pragma unroll
      for (int dt = 0; dt < 4; ++dt) {
        unsigned int u0 = pk2(o[t][dt][0] * inv, o[t][dt][1] * inv);
        unsigned int u1 = pk2(o[t][dt][2] * inv, o[t][dt][3] * inv);
        *(unsigned int*)&Ob[base + dt * 16 + lg * 4] = u0;
        *(unsigned int*)&Ob[base + dt * 16 + lg * 4 + 2] = u1;
      }
    }
  }
}

extern "C" void kernel_launch(void* const* d_in, const int* in_sizes, int n_in,
                              void* d_out, int out_size, void* d_ws,
                              size_t ws_size, hipStream_t stream) {
  const float* x = (const float*)d_in[0];
  const float* w_qkv = (const float*)d_in[1];
  const float* w_proj = (const float*)d_in[2];
  float* out = (float*)d_out;

  char* ws = (char*)d_ws;
  size_t off = 0;
  unsigned short* x_bf = (unsigned short*)(ws + off);
  off += (size_t)M_ROWS * D_MODEL * 2;
  unsigned short* wqkv_t = (unsigned short*)(ws + off);
  off += (size_t)D_MODEL * 3 * D_MODEL * 2;
  unsigned short* wproj_t = (unsigned short*)(ws + off);
  off += (size_t)D_MODEL * D_MODEL * 2;
  unsigned short* Qb = (unsigned short*)(ws + off);
  off += (size_t)BH_TOT * T_SEQ * HEAD_DIM * 2;
  unsigned short* Kb = (unsigned short*)(ws + off);
  off += (size_t)BH_TOT * T_SEQ * HEAD_DIM * 2;
  unsigned short* Vt = (unsigned short*)(ws + off);
  off += (size_t)BH_TOT * T_SEQ * HEAD_DIM * 2;
  unsigned short* Ob = (unsigned short*)(ws + off);
  off += (size_t)M_ROWS * D_MODEL * 2;

  int n1 = M_ROWS * D_MODEL;
  cvt_f32_bf16<<<(n1 / 4 + 255) / 256, 256, 0, stream>>>(x, x_bf, n1);
  cvt_transpose<<<dim3(3 * D_MODEL / 32, D_MODEL / 32), 256, 0, stream>>>(
      w_qkv, wqkv_t, D_MODEL, 3 * D_MODEL);
  cvt_transpose<<<dim3(D_MODEL / 32, D_MODEL / 32), 256, 0, stream>>>(
      w_proj, wproj_t, D_MODEL, D_MODEL);

  gemm_bf16<0><<<dim3(3 * D_MODEL / 128, M_ROWS / 128), 256, 0, stream>>>(
      x_bf, wqkv_t, M_ROWS, 3 * D_MODEL, D_MODEL, Qb, Kb, Vt, nullptr);

  attn_fwd<<<dim3(BH_TOT, 8), 256, 0, stream>>>(Qb, Kb, Vt, Ob);

  gemm_bf16<1><<<dim3(D_MODEL / 128, M_ROWS / 128), 256, 0, stream>>>(
      Ob, wproj_t, M_ROWS, D_MODEL, D_MODEL, nullptr, nullptr, nullptr, out);
}